// Round 1
// baseline (2718.212 us; speedup 1.0000x reference)
//
#include <hip/hip_runtime.h>
#include <hip/hip_bf16.h>

// Problem constants
#define NQ    12
#define SDIM  4096      // 2^12 statevector
#define BATCH 8192
#define FDIM  8192

// GEMM tile config: xr[8192][4096] = x[8192][8192] @ W_red[4096][8192]^T
#define BM 128
#define BN 128
#define BK 64

using bf16x8 = __attribute__((ext_vector_type(8))) short;
using f32x4  = __attribute__((ext_vector_type(4))) float;

__device__ __forceinline__ unsigned short f2bf(float f) {
    unsigned u = __float_as_uint(f);
    u += 0x7FFFu + ((u >> 16) & 1u);          // RNE to bf16
    return (unsigned short)(u >> 16);
}
__device__ __forceinline__ float bf2f(unsigned short h) {
    return __uint_as_float(((unsigned)h) << 16);
}

// ---------------------------------------------------------------------------
// Kernel 1: split-bf16 MFMA GEMM.  xr = x @ W^T + b_red
// a = a_hi + a_lo (bf16 each); acc += Ah*Bh + Ah*Bl + Al*Bh  (~fp32 accuracy)
// 128x128 tile, BK=64, 4 waves (2x2), each wave 64x64 via 4x4 frags of 16x16x32.
// LDS tiles XOR-swizzled (byte ^= (row&7)<<4) -> conflict-free ds_read_b128.
// ---------------------------------------------------------------------------
__global__ __launch_bounds__(256, 2)
void vqc_gemm_split(const float* __restrict__ X, const float* __restrict__ W,
                    const float* __restrict__ bred, float* __restrict__ XR)
{
    __shared__ unsigned char lds[65536];
    unsigned char* Ah = lds;
    unsigned char* Al = lds + 16384;
    unsigned char* Bh = lds + 32768;
    unsigned char* Bl = lds + 49152;

    const int t    = threadIdx.x;
    const int lane = t & 63;
    const int w    = t >> 6;
    const int wr   = w >> 1, wc = w & 1;
    const int bm0  = blockIdx.y * BM;
    const int bn0  = blockIdx.x * BN;
    const int l16  = lane & 15;
    const int lg   = lane >> 4;

    f32x4 acc[4][4] = {};

    for (int bk = 0; bk < FDIM; bk += BK) {
        // ---- global loads (fp32): 8 float4 each for A and B per thread ----
        float4 av[8], bv[8];
        #pragma unroll
        for (int i = 0; i < 8; i++) {
            int p   = i * 256 + t;
            int row = p >> 4, c4 = p & 15;
            av[i] = *(const float4*)(X + (size_t)(bm0 + row) * FDIM + bk + c4 * 4);
            bv[i] = *(const float4*)(W + (size_t)(bn0 + row) * FDIM + bk + c4 * 4);
        }
        __syncthreads();   // previous compute done; LDS free
        // ---- convert to hi/lo bf16, swizzled ds_write (8B chunks) ----
        #pragma unroll
        for (int i = 0; i < 8; i++) {
            int p   = i * 256 + t;
            int row = p >> 4, c4 = p & 15;
            unsigned addr = ((unsigned)(row * 128 + c4 * 8)) ^ ((unsigned)((row & 7) << 4));
            {
                float4 v = av[i];
                unsigned short h0 = f2bf(v.x), h1 = f2bf(v.y), h2 = f2bf(v.z), h3 = f2bf(v.w);
                unsigned short l0 = f2bf(v.x - bf2f(h0)), l1 = f2bf(v.y - bf2f(h1));
                unsigned short l2 = f2bf(v.z - bf2f(h2)), l3 = f2bf(v.w - bf2f(h3));
                *(uint2*)(Ah + addr) = make_uint2((unsigned)h0 | ((unsigned)h1 << 16),
                                                  (unsigned)h2 | ((unsigned)h3 << 16));
                *(uint2*)(Al + addr) = make_uint2((unsigned)l0 | ((unsigned)l1 << 16),
                                                  (unsigned)l2 | ((unsigned)l3 << 16));
            }
            {
                float4 v = bv[i];
                unsigned short h0 = f2bf(v.x), h1 = f2bf(v.y), h2 = f2bf(v.z), h3 = f2bf(v.w);
                unsigned short l0 = f2bf(v.x - bf2f(h0)), l1 = f2bf(v.y - bf2f(h1));
                unsigned short l2 = f2bf(v.z - bf2f(h2)), l3 = f2bf(v.w - bf2f(h3));
                *(uint2*)(Bh + addr) = make_uint2((unsigned)h0 | ((unsigned)h1 << 16),
                                                  (unsigned)h2 | ((unsigned)h3 << 16));
                *(uint2*)(Bl + addr) = make_uint2((unsigned)l0 | ((unsigned)l1 << 16),
                                                  (unsigned)l2 | ((unsigned)l3 << 16));
            }
        }
        __syncthreads();
        // ---- MFMA: 2 k-subs of 32; 48 MFMA per ksub per wave ----
        #pragma unroll
        for (int ks = 0; ks < 2; ks++) {
            bf16x8 aH[4], aL[4], bH[4], bL[4];
            const int slot = ks * 4 + lg;
            #pragma unroll
            for (int m = 0; m < 4; m++) {
                int row = wr * 64 + m * 16 + l16;
                unsigned off = ((unsigned)(row * 128 + slot * 16)) ^ ((unsigned)((row & 7) << 4));
                aH[m] = *(const bf16x8*)(Ah + off);
                aL[m] = *(const bf16x8*)(Al + off);
            }
            #pragma unroll
            for (int n = 0; n < 4; n++) {
                int row = wc * 64 + n * 16 + l16;
                unsigned off = ((unsigned)(row * 128 + slot * 16)) ^ ((unsigned)((row & 7) << 4));
                bH[n] = *(const bf16x8*)(Bh + off);
                bL[n] = *(const bf16x8*)(Bl + off);
            }
            #pragma unroll
            for (int m = 0; m < 4; m++)
                #pragma unroll
                for (int n = 0; n < 4; n++) {
                    acc[m][n] = __builtin_amdgcn_mfma_f32_16x16x32_bf16(aH[m], bH[n], acc[m][n], 0, 0, 0);
                    acc[m][n] = __builtin_amdgcn_mfma_f32_16x16x32_bf16(aH[m], bL[n], acc[m][n], 0, 0, 0);
                    acc[m][n] = __builtin_amdgcn_mfma_f32_16x16x32_bf16(aL[m], bH[n], acc[m][n], 0, 0, 0);
                }
        }
    }
    // ---- epilogue: C/D layout col=lane&15, row=(lane>>4)*4+j (m89-verified) ----
    #pragma unroll
    for (int n = 0; n < 4; n++) {
        int col = bn0 + wc * 64 + n * 16 + l16;
        float bb = bred[col];
        #pragma unroll
        for (int m = 0; m < 4; m++) {
            int rowb = bm0 + wr * 64 + m * 16 + lg * 4;
            #pragma unroll
            for (int j = 0; j < 4; j++)
                XR[(size_t)(rowb + j) * SDIM + col] = acc[m][n][j] + bb;
        }
    }
}

// ---------------------------------------------------------------------------
// Kernel 2: per-row quantum circuit + Z-features + MLP + sigmoid.
// One block (256 thr) per batch row; statevector in LDS (16 KB).
// ---------------------------------------------------------------------------
__global__ __launch_bounds__(256)
void vqc_circuit(const float* __restrict__ XR, const float* __restrict__ theta,
                 const float* __restrict__ W1, const float* __restrict__ b1,
                 const float* __restrict__ W2, const float* __restrict__ b2,
                 const float* __restrict__ W3, const float* __restrict__ b3,
                 float* __restrict__ OUT)
{
    __shared__ float s[SDIM];
    __shared__ float cs_[36], sn_[36];
    __shared__ float wred[4];
    __shared__ float mred[48];

    const int t = threadIdx.x;
    const int lane = t & 63;
    const int w = t >> 6;
    const size_t row = blockIdx.x;
    const float* src = XR + row * SDIM;

    if (t < 36) { float th = theta[t] * 0.5f; cs_[t] = cosf(th); sn_[t] = sinf(th); }

    // load row + sum of squares
    float ss = 0.f;
    #pragma unroll
    for (int i = 0; i < 4; i++) {
        float4 v = *(const float4*)(src + (size_t)(i * 256 + t) * 4);
        ss += v.x * v.x + v.y * v.y + v.z * v.z + v.w * v.w;
        *(float4*)(s + (i * 256 + t) * 4) = v;
    }
    #pragma unroll
    for (int off = 32; off; off >>= 1) ss += __shfl_down(ss, off);
    if (lane == 0) wred[w] = ss;
    __syncthreads();
    const float scale = 1.f / (sqrtf(wred[0] + wred[1] + wred[2] + wred[3]) + 1e-10f);
    #pragma unroll
    for (int j = 0; j < 16; j++) s[j * 256 + t] *= scale;

    // composite CNOT-layer permutation: g = CNOT0∘CNOT1∘...∘CNOT11 (theta-free)
    int gperm[16];
    #pragma unroll
    for (int j = 0; j < 16; j++) {
        int p = j * 256 + t;
        #pragma unroll
        for (int q = 11; q >= 0; q--) {
            const int tq = (q + 1) % 12;
            const int cm = 1 << (11 - q);
            const int tm = 1 << (11 - tq);
            if (p & cm) p ^= tm;
        }
        gperm[j] = p;
    }
    __syncthreads();

    for (int l = 0; l < 3; l++) {
        // 12 RY gates; each thread owns 8 disjoint (i0,i1) pairs
        #pragma unroll
        for (int q = 0; q < 12; q++) {
            const float c = cs_[l * 12 + q], sn = sn_[l * 12 + q];
            const int R = 1 << (11 - q);
            #pragma unroll
            for (int j = 0; j < 8; j++) {
                int p  = j * 256 + t;
                int i0 = ((p & ~(R - 1)) << 1) | (p & (R - 1));
                int i1 = i0 | R;
                float a0 = s[i0], a1 = s[i1];
                s[i0] = c * a0 - sn * a1;
                s[i1] = sn * a0 + c * a1;
            }
            __syncthreads();
        }
        // composite CNOT layer: gather then scatter-back
        float tmp[16];
        #pragma unroll
        for (int j = 0; j < 16; j++) tmp[j] = s[gperm[j]];
        __syncthreads();
        #pragma unroll
        for (int j = 0; j < 16; j++) s[j * 256 + t] = tmp[j];
        __syncthreads();
    }

    // Z-expectations: m[q] = sum_i (+/-) s[i]^2
    float mq[12] = {};
    #pragma unroll
    for (int j = 0; j < 16; j++) {
        int i = j * 256 + t;
        float p = s[i] * s[i];
        #pragma unroll
        for (int q = 0; q < 12; q++)
            mq[q] += ((i >> (11 - q)) & 1) ? -p : p;
    }
    #pragma unroll
    for (int q = 0; q < 12; q++)
        #pragma unroll
        for (int off = 32; off; off >>= 1) mq[q] += __shfl_down(mq[q], off);
    if (lane == 0) {
        #pragma unroll
        for (int q = 0; q < 12; q++) mred[w * 12 + q] = mq[q];
    }
    __syncthreads();

    if (t == 0) {
        float m[12];
        #pragma unroll
        for (int q = 0; q < 12; q++)
            m[q] = mred[q] + mred[12 + q] + mred[24 + q] + mred[36 + q];
        float h1[32];
        for (int k = 0; k < 32; k++) {
            float z = b1[k];
            for (int j = 0; j < 12; j++) z += W1[k * 12 + j] * m[j];
            h1[k] = fmaxf(z, 0.f);
        }
        float h2[16];
        for (int k = 0; k < 16; k++) {
            float z = b2[k];
            for (int j = 0; j < 32; j++) z += W2[k * 32 + j] * h1[j];
            h2[k] = fmaxf(z, 0.f);
        }
        float z = b3[0];
        for (int j = 0; j < 16; j++) z += W3[j] * h2[j];
        OUT[row] = 1.f / (1.f + expf(-z));
    }
}

// ---------------------------------------------------------------------------
extern "C" void kernel_launch(void* const* d_in, const int* in_sizes, int n_in,
                              void* d_out, int out_size, void* d_ws, size_t ws_size,
                              hipStream_t stream)
{
    const float* x     = (const float*)d_in[0];
    const float* W_red = (const float*)d_in[1];
    const float* b_red = (const float*)d_in[2];
    const float* theta = (const float*)d_in[3];
    const float* W1    = (const float*)d_in[4];
    const float* b1    = (const float*)d_in[5];
    const float* W2    = (const float*)d_in[6];
    const float* b2    = (const float*)d_in[7];
    const float* W3    = (const float*)d_in[8];
    const float* b3    = (const float*)d_in[9];
    float* out = (float*)d_out;
    float* xr  = (float*)d_ws;   // needs BATCH*SDIM*4 = 128 MB of workspace

    dim3 g1(SDIM / BN, BATCH / BM);   // (32, 64)
    vqc_gemm_split<<<g1, 256, 0, stream>>>(x, W_red, b_red, xr);
    vqc_circuit<<<BATCH, 256, 0, stream>>>(xr, theta, W1, b1, W2, b2, W3, b3, out);
}

// Round 2
// 1386.233 us; speedup vs baseline: 1.9609x; 1.9609x over previous
//
#include <hip/hip_runtime.h>
#include <hip/hip_bf16.h>

// Problem constants
#define NQ    12
#define SDIM  4096      // 2^12 statevector
#define BATCH 8192
#define FDIM  8192

using bf16x8 = __attribute__((ext_vector_type(8))) short;
using f16x8  = __attribute__((ext_vector_type(8))) _Float16;
using f32x4  = __attribute__((ext_vector_type(4))) float;

__device__ __forceinline__ unsigned short f2bf(float f) {
    unsigned u = __float_as_uint(f);
    u += 0x7FFFu + ((u >> 16) & 1u);          // RNE to bf16
    return (unsigned short)(u >> 16);
}
__device__ __forceinline__ float bf2f(unsigned short h) {
    return __uint_as_float(((unsigned)h) << 16);
}

__device__ __forceinline__ void gl_lds16(const void* g, void* l) {
    __builtin_amdgcn_global_load_lds(
        (const __attribute__((address_space(1))) void*)g,
        (__attribute__((address_space(3))) void*)l, 16, 0, 0);
}

// ---------------------------------------------------------------------------
// Pre-pass: fp32 -> fp16 conversion (X and W), vectorized 32B read / 16B write
// ---------------------------------------------------------------------------
__global__ __launch_bounds__(256)
void cvt_fp16(const float* __restrict__ in, _Float16* __restrict__ out, unsigned n8)
{
    unsigned i = blockIdx.x * 256 + threadIdx.x;
    const unsigned stride = gridDim.x * 256;
    for (; i < n8; i += stride) {
        float4 a = ((const float4*)in)[2 * i];
        float4 b = ((const float4*)in)[2 * i + 1];
        f16x8 o;
        o[0] = (_Float16)a.x; o[1] = (_Float16)a.y; o[2] = (_Float16)a.z; o[3] = (_Float16)a.w;
        o[4] = (_Float16)b.x; o[5] = (_Float16)b.y; o[6] = (_Float16)b.z; o[7] = (_Float16)b.w;
        ((f16x8*)out)[i] = o;
    }
}

// ---------------------------------------------------------------------------
// Fast path GEMM: pure fp16 MFMA, m97 structure (global_load_lds width=16,
// 128x128 tile, BK=64, 2 barriers/K-step, linear LDS).
// xr(fp16) = fp16(X) @ fp16(W)^T + b_red
// ---------------------------------------------------------------------------
__global__ __launch_bounds__(256, 2)
void vqc_gemm_f16(const _Float16* __restrict__ Xh, const _Float16* __restrict__ Wh,
                  const float* __restrict__ bred, _Float16* __restrict__ XR)
{
    __shared__ _Float16 Alds[128 * 64];
    __shared__ _Float16 Blds[128 * 64];

    const int t    = threadIdx.x;
    const int lane = t & 63;
    const int wv   = t >> 6;
    const int wr   = wv >> 1, wc = wv & 1;
    const int l16  = lane & 15, lg = lane >> 4;
    const int bm0  = blockIdx.y * 128;
    const int bn0  = blockIdx.x * 128;
    const int lr   = lane >> 3;          // 0..7 row within 8-row chunk
    const int lc   = (lane & 7) * 8;     // fp16 col offset (16B per lane)

    f32x4 acc[4][4] = {};

    for (int bk = 0; bk < FDIM; bk += 64) {
        // stage A+B tiles: wave wv covers rows [wv*32, wv*32+32), 4 chunks of 8 rows
        #pragma unroll
        for (int i = 0; i < 4; i++) {
            int r0 = wv * 32 + i * 8;
            gl_lds16(Xh + (size_t)(bm0 + r0 + lr) * FDIM + bk + lc, (char*)Alds + r0 * 128);
            gl_lds16(Wh + (size_t)(bn0 + r0 + lr) * FDIM + bk + lc, (char*)Blds + r0 * 128);
        }
        __syncthreads();   // drains vmcnt -> tiles ready
        #pragma unroll
        for (int ks = 0; ks < 2; ks++) {
            f16x8 af[4], bf_[4];
            #pragma unroll
            for (int m = 0; m < 4; m++) {
                int row = wr * 64 + m * 16 + l16;
                af[m] = *(const f16x8*)((const char*)Alds + row * 128 + ks * 64 + lg * 16);
            }
            #pragma unroll
            for (int n = 0; n < 4; n++) {
                int row = wc * 64 + n * 16 + l16;
                bf_[n] = *(const f16x8*)((const char*)Blds + row * 128 + ks * 64 + lg * 16);
            }
            #pragma unroll
            for (int m = 0; m < 4; m++)
                #pragma unroll
                for (int n = 0; n < 4; n++)
                    acc[m][n] = __builtin_amdgcn_mfma_f32_16x16x32_f16(af[m], bf_[n], acc[m][n], 0, 0, 0);
        }
        __syncthreads();   // all waves done reading before next overwrite
    }
    // epilogue: C/D layout col=lane&15, row=(lane>>4)*4+j (m89-verified)
    #pragma unroll
    for (int n = 0; n < 4; n++) {
        int col = bn0 + wc * 64 + n * 16 + l16;
        float bb = bred[col];
        #pragma unroll
        for (int m = 0; m < 4; m++) {
            int rowb = bm0 + wr * 64 + m * 16 + lg * 4;
            #pragma unroll
            for (int j = 0; j < 4; j++)
                XR[(size_t)(rowb + j) * SDIM + col] = (_Float16)(acc[m][n][j] + bb);
        }
    }
}

// ---------------------------------------------------------------------------
// Fallback GEMM (round-1 proven): split-bf16 3-term MFMA, fp32 in/out.
// ---------------------------------------------------------------------------
__global__ __launch_bounds__(256, 2)
void vqc_gemm_split(const float* __restrict__ X, const float* __restrict__ W,
                    const float* __restrict__ bred, float* __restrict__ XR)
{
    __shared__ unsigned char lds[65536];
    unsigned char* Ah = lds;
    unsigned char* Al = lds + 16384;
    unsigned char* Bh = lds + 32768;
    unsigned char* Bl = lds + 49152;

    const int t    = threadIdx.x;
    const int lane = t & 63;
    const int w    = t >> 6;
    const int wr   = w >> 1, wc = w & 1;
    const int bm0  = blockIdx.y * 128;
    const int bn0  = blockIdx.x * 128;
    const int l16  = lane & 15;
    const int lg   = lane >> 4;

    f32x4 acc[4][4] = {};

    for (int bk = 0; bk < FDIM; bk += 64) {
        float4 av[8], bv[8];
        #pragma unroll
        for (int i = 0; i < 8; i++) {
            int p   = i * 256 + t;
            int row = p >> 4, c4 = p & 15;
            av[i] = *(const float4*)(X + (size_t)(bm0 + row) * FDIM + bk + c4 * 4);
            bv[i] = *(const float4*)(W + (size_t)(bn0 + row) * FDIM + bk + c4 * 4);
        }
        __syncthreads();
        #pragma unroll
        for (int i = 0; i < 8; i++) {
            int p   = i * 256 + t;
            int row = p >> 4, c4 = p & 15;
            unsigned addr = ((unsigned)(row * 128 + c4 * 8)) ^ ((unsigned)((row & 7) << 4));
            {
                float4 v = av[i];
                unsigned short h0 = f2bf(v.x), h1 = f2bf(v.y), h2 = f2bf(v.z), h3 = f2bf(v.w);
                unsigned short l0 = f2bf(v.x - bf2f(h0)), l1 = f2bf(v.y - bf2f(h1));
                unsigned short l2 = f2bf(v.z - bf2f(h2)), l3 = f2bf(v.w - bf2f(h3));
                *(uint2*)(Ah + addr) = make_uint2((unsigned)h0 | ((unsigned)h1 << 16),
                                                  (unsigned)h2 | ((unsigned)h3 << 16));
                *(uint2*)(Al + addr) = make_uint2((unsigned)l0 | ((unsigned)l1 << 16),
                                                  (unsigned)l2 | ((unsigned)l3 << 16));
            }
            {
                float4 v = bv[i];
                unsigned short h0 = f2bf(v.x), h1 = f2bf(v.y), h2 = f2bf(v.z), h3 = f2bf(v.w);
                unsigned short l0 = f2bf(v.x - bf2f(h0)), l1 = f2bf(v.y - bf2f(h1));
                unsigned short l2 = f2bf(v.z - bf2f(h2)), l3 = f2bf(v.w - bf2f(h3));
                *(uint2*)(Bh + addr) = make_uint2((unsigned)h0 | ((unsigned)h1 << 16),
                                                  (unsigned)h2 | ((unsigned)h3 << 16));
                *(uint2*)(Bl + addr) = make_uint2((unsigned)l0 | ((unsigned)l1 << 16),
                                                  (unsigned)l2 | ((unsigned)l3 << 16));
            }
        }
        __syncthreads();
        #pragma unroll
        for (int ks = 0; ks < 2; ks++) {
            bf16x8 aH[4], aL[4], bH[4], bL[4];
            const int slot = ks * 4 + lg;
            #pragma unroll
            for (int m = 0; m < 4; m++) {
                int row = wr * 64 + m * 16 + l16;
                unsigned off = ((unsigned)(row * 128 + slot * 16)) ^ ((unsigned)((row & 7) << 4));
                aH[m] = *(const bf16x8*)(Ah + off);
                aL[m] = *(const bf16x8*)(Al + off);
            }
            #pragma unroll
            for (int n = 0; n < 4; n++) {
                int row = wc * 64 + n * 16 + l16;
                unsigned off = ((unsigned)(row * 128 + slot * 16)) ^ ((unsigned)((row & 7) << 4));
                bH[n] = *(const bf16x8*)(Bh + off);
                bL[n] = *(const bf16x8*)(Bl + off);
            }
            #pragma unroll
            for (int m = 0; m < 4; m++)
                #pragma unroll
                for (int n = 0; n < 4; n++) {
                    acc[m][n] = __builtin_amdgcn_mfma_f32_16x16x32_bf16(aH[m], bH[n], acc[m][n], 0, 0, 0);
                    acc[m][n] = __builtin_amdgcn_mfma_f32_16x16x32_bf16(aH[m], bL[n], acc[m][n], 0, 0, 0);
                    acc[m][n] = __builtin_amdgcn_mfma_f32_16x16x32_bf16(aL[m], bH[n], acc[m][n], 0, 0, 0);
                }
        }
    }
    #pragma unroll
    for (int n = 0; n < 4; n++) {
        int col = bn0 + wc * 64 + n * 16 + l16;
        float bb = bred[col];
        #pragma unroll
        for (int m = 0; m < 4; m++) {
            int rowb = bm0 + wr * 64 + m * 16 + lg * 4;
            #pragma unroll
            for (int j = 0; j < 4; j++)
                XR[(size_t)(rowb + j) * SDIM + col] = acc[m][n][j] + bb;
        }
    }
}

// ---------------------------------------------------------------------------
// Kernel 2: per-row quantum circuit + Z-features + MLP + sigmoid.
// One block (256 thr) per batch row; statevector in LDS (16 KB).
// Templated on xr dtype (fp16 fast path / fp32 fallback).
// ---------------------------------------------------------------------------
template <typename T>
__global__ __launch_bounds__(256)
void vqc_circuit(const T* __restrict__ XR, const float* __restrict__ theta,
                 const float* __restrict__ W1, const float* __restrict__ b1,
                 const float* __restrict__ W2, const float* __restrict__ b2,
                 const float* __restrict__ W3, const float* __restrict__ b3,
                 float* __restrict__ OUT)
{
    __shared__ float s[SDIM];
    __shared__ float cs_[36], sn_[36];
    __shared__ float wred[4];
    __shared__ float mred[48];

    const int t = threadIdx.x;
    const int lane = t & 63;
    const int w = t >> 6;
    const size_t row = blockIdx.x;
    const T* src = XR + row * SDIM;

    if (t < 36) { float th = theta[t] * 0.5f; cs_[t] = cosf(th); sn_[t] = sinf(th); }

    // load row + sum of squares
    float ss = 0.f;
    if constexpr (sizeof(T) == 2) {
        #pragma unroll
        for (int i = 0; i < 2; i++) {
            f16x8 v = *(const f16x8*)(src + (size_t)(i * 256 + t) * 8);
            float f[8];
            #pragma unroll
            for (int j = 0; j < 8; j++) { f[j] = (float)v[j]; ss += f[j] * f[j]; }
            #pragma unroll
            for (int j = 0; j < 8; j++) s[(i * 256 + t) * 8 + j] = f[j];
        }
    } else {
        #pragma unroll
        for (int i = 0; i < 4; i++) {
            float4 v = *(const float4*)((const float*)src + (size_t)(i * 256 + t) * 4);
            ss += v.x * v.x + v.y * v.y + v.z * v.z + v.w * v.w;
            *(float4*)(s + (i * 256 + t) * 4) = v;
        }
    }
    #pragma unroll
    for (int off = 32; off; off >>= 1) ss += __shfl_down(ss, off);
    if (lane == 0) wred[w] = ss;
    __syncthreads();
    const float scale = 1.f / (sqrtf(wred[0] + wred[1] + wred[2] + wred[3]) + 1e-10f);
    #pragma unroll
    for (int j = 0; j < 16; j++) s[j * 256 + t] *= scale;

    // composite CNOT-layer permutation (theta-free)
    int gperm[16];
    #pragma unroll
    for (int j = 0; j < 16; j++) {
        int p = j * 256 + t;
        #pragma unroll
        for (int q = 11; q >= 0; q--) {
            const int tq = (q + 1) % 12;
            const int cm = 1 << (11 - q);
            const int tm = 1 << (11 - tq);
            if (p & cm) p ^= tm;
        }
        gperm[j] = p;
    }
    __syncthreads();

    for (int l = 0; l < 3; l++) {
        #pragma unroll
        for (int q = 0; q < 12; q++) {
            const float c = cs_[l * 12 + q], sn = sn_[l * 12 + q];
            const int R = 1 << (11 - q);
            #pragma unroll
            for (int j = 0; j < 8; j++) {
                int p  = j * 256 + t;
                int i0 = ((p & ~(R - 1)) << 1) | (p & (R - 1));
                int i1 = i0 | R;
                float a0 = s[i0], a1 = s[i1];
                s[i0] = c * a0 - sn * a1;
                s[i1] = sn * a0 + c * a1;
            }
            __syncthreads();
        }
        float tmp[16];
        #pragma unroll
        for (int j = 0; j < 16; j++) tmp[j] = s[gperm[j]];
        __syncthreads();
        #pragma unroll
        for (int j = 0; j < 16; j++) s[j * 256 + t] = tmp[j];
        __syncthreads();
    }

    // Z-expectations
    float mq[12] = {};
    #pragma unroll
    for (int j = 0; j < 16; j++) {
        int i = j * 256 + t;
        float p = s[i] * s[i];
        #pragma unroll
        for (int q = 0; q < 12; q++)
            mq[q] += ((i >> (11 - q)) & 1) ? -p : p;
    }
    #pragma unroll
    for (int q = 0; q < 12; q++)
        #pragma unroll
        for (int off = 32; off; off >>= 1) mq[q] += __shfl_down(mq[q], off);
    if (lane == 0) {
        #pragma unroll
        for (int q = 0; q < 12; q++) mred[w * 12 + q] = mq[q];
    }
    __syncthreads();

    if (t == 0) {
        float m[12];
        #pragma unroll
        for (int q = 0; q < 12; q++)
            m[q] = mred[q] + mred[12 + q] + mred[24 + q] + mred[36 + q];
        float h1[32];
        for (int k = 0; k < 32; k++) {
            float z = b1[k];
            for (int j = 0; j < 12; j++) z += W1[k * 12 + j] * m[j];
            h1[k] = fmaxf(z, 0.f);
        }
        float h2[16];
        for (int k = 0; k < 16; k++) {
            float z = b2[k];
            for (int j = 0; j < 32; j++) z += W2[k * 32 + j] * h1[j];
            h2[k] = fmaxf(z, 0.f);
        }
        float z = b3[0];
        for (int j = 0; j < 16; j++) z += W3[j] * h2[j];
        OUT[row] = 1.f / (1.f + expf(-z));
    }
}

// ---------------------------------------------------------------------------
extern "C" void kernel_launch(void* const* d_in, const int* in_sizes, int n_in,
                              void* d_out, int out_size, void* d_ws, size_t ws_size,
                              hipStream_t stream)
{
    const float* x     = (const float*)d_in[0];
    const float* W_red = (const float*)d_in[1];
    const float* b_red = (const float*)d_in[2];
    const float* theta = (const float*)d_in[3];
    const float* W1    = (const float*)d_in[4];
    const float* b1    = (const float*)d_in[5];
    const float* W2    = (const float*)d_in[6];
    const float* b2    = (const float*)d_in[7];
    const float* W3    = (const float*)d_in[8];
    const float* b3    = (const float*)d_in[9];
    float* out = (float*)d_out;

    const size_t SZ_XH = (size_t)BATCH * FDIM * 2;   // 128 MiB
    const size_t SZ_WH = (size_t)SDIM * FDIM * 2;    //  64 MiB
    const size_t SZ_XR = (size_t)BATCH * SDIM * 2;   //  64 MiB
    const size_t NEED  = SZ_XH + SZ_WH + SZ_XR;      // 256 MiB

    if (ws_size >= NEED) {
        _Float16* Xh = (_Float16*)d_ws;
        _Float16* Wh = (_Float16*)((char*)d_ws + SZ_XH);
        _Float16* xr = (_Float16*)((char*)d_ws + SZ_XH + SZ_WH);
        cvt_fp16<<<2048, 256, 0, stream>>>(x, Xh, (unsigned)((size_t)BATCH * FDIM / 8));
        cvt_fp16<<<1024, 256, 0, stream>>>(W_red, Wh, (unsigned)((size_t)SDIM * FDIM / 8));
        dim3 g1(SDIM / 128, BATCH / 128);   // (32, 64)
        vqc_gemm_f16<<<g1, 256, 0, stream>>>(Xh, Wh, b_red, xr);
        vqc_circuit<_Float16><<<BATCH, 256, 0, stream>>>(xr, theta, W1, b1, W2, b2, W3, b3, out);
    } else {
        float* xr = (float*)d_ws;   // 128 MiB
        dim3 g1(SDIM / 128, BATCH / 128);
        vqc_gemm_split<<<g1, 256, 0, stream>>>(x, W_red, b_red, xr);
        vqc_circuit<float><<<BATCH, 256, 0, stream>>>(xr, theta, W1, b1, W2, b2, W3, b3, out);
    }
}

// Round 4
// 1184.206 us; speedup vs baseline: 2.2954x; 1.1706x over previous
//
#include <hip/hip_runtime.h>
#include <hip/hip_bf16.h>

// Problem constants
#define NQ    12
#define SDIM  4096      // 2^12 statevector
#define BATCH 8192
#define FDIM  8192

using bf16x8 = __attribute__((ext_vector_type(8))) short;
using f16x8  = __attribute__((ext_vector_type(8))) _Float16;
using f32x4  = __attribute__((ext_vector_type(4))) float;

__device__ __forceinline__ unsigned short f2bf(float f) {
    unsigned u = __float_as_uint(f);
    u += 0x7FFFu + ((u >> 16) & 1u);          // RNE to bf16
    return (unsigned short)(u >> 16);
}
__device__ __forceinline__ float bf2f(unsigned short h) {
    return __uint_as_float(((unsigned)h) << 16);
}

__device__ __forceinline__ void gl_lds16(const void* g, void* l) {
    __builtin_amdgcn_global_load_lds(
        (const __attribute__((address_space(1))) void*)g,
        (__attribute__((address_space(3))) void*)l, 16, 0, 0);
}

// ---------------------------------------------------------------------------
// Pre-pass: fp32 -> fp16 conversion (X and W), vectorized 32B read / 16B write
// ---------------------------------------------------------------------------
__global__ __launch_bounds__(256)
void cvt_fp16(const float* __restrict__ in, _Float16* __restrict__ out, unsigned n8)
{
    unsigned i = blockIdx.x * 256 + threadIdx.x;
    const unsigned stride = gridDim.x * 256;
    for (; i < n8; i += stride) {
        float4 a = ((const float4*)in)[2 * i];
        float4 b = ((const float4*)in)[2 * i + 1];
        f16x8 o;
        o[0] = (_Float16)a.x; o[1] = (_Float16)a.y; o[2] = (_Float16)a.z; o[3] = (_Float16)a.w;
        o[4] = (_Float16)b.x; o[5] = (_Float16)b.y; o[6] = (_Float16)b.z; o[7] = (_Float16)b.w;
        ((f16x8*)out)[i] = o;
    }
}

// ---------------------------------------------------------------------------
// Fast path GEMM: pure fp16 MFMA, m97 structure + T2 swizzle done per rule #21:
// linear global_load_lds dest, PRE-SWIZZLED global source column, XOR-swizzled
// ds_read.  chunk' = chunk ^ (row&7), 16B granules within each 128B row.
// ---------------------------------------------------------------------------
__global__ __launch_bounds__(256, 2)
void vqc_gemm_f16(const _Float16* __restrict__ Xh, const _Float16* __restrict__ Wh,
                  const float* __restrict__ bred, _Float16* __restrict__ XR)
{
    __shared__ _Float16 Alds[128 * 64];
    __shared__ _Float16 Blds[128 * 64];

    const int t    = threadIdx.x;
    const int lane = t & 63;
    const int wv   = t >> 6;
    const int wr   = wv >> 1, wc = wv & 1;
    const int l16  = lane & 15, lg = lane >> 4;
    const int bm0  = blockIdx.y * 128;
    const int bn0  = blockIdx.x * 128;
    const int lr   = lane >> 3;                      // row within 8-row chunk
    const int lcsw = ((lane & 7) ^ lr) * 8;          // pre-swizzled fp16 col

    f32x4 acc[4][4] = {};

    for (int bk = 0; bk < FDIM; bk += 64) {
        #pragma unroll
        for (int i = 0; i < 4; i++) {
            int r0 = wv * 32 + i * 8;
            gl_lds16(Xh + (size_t)(bm0 + r0 + lr) * FDIM + bk + lcsw, (char*)Alds + r0 * 128);
            gl_lds16(Wh + (size_t)(bn0 + r0 + lr) * FDIM + bk + lcsw, (char*)Blds + r0 * 128);
        }
        __syncthreads();   // drains vmcnt -> tiles ready
        #pragma unroll
        for (int ks = 0; ks < 2; ks++) {
            f16x8 af[4], bf_[4];
            #pragma unroll
            for (int m = 0; m < 4; m++) {
                int row = wr * 64 + m * 16 + l16;
                unsigned off = ((unsigned)(row * 128 + ks * 64 + lg * 16)) ^ ((unsigned)((row & 7) << 4));
                af[m] = *(const f16x8*)((const char*)Alds + off);
            }
            #pragma unroll
            for (int n = 0; n < 4; n++) {
                int row = wc * 64 + n * 16 + l16;
                unsigned off = ((unsigned)(row * 128 + ks * 64 + lg * 16)) ^ ((unsigned)((row & 7) << 4));
                bf_[n] = *(const f16x8*)((const char*)Blds + off);
            }
            #pragma unroll
            for (int m = 0; m < 4; m++)
                #pragma unroll
                for (int n = 0; n < 4; n++)
                    acc[m][n] = __builtin_amdgcn_mfma_f32_16x16x32_f16(af[m], bf_[n], acc[m][n], 0, 0, 0);
        }
        __syncthreads();
    }
    // epilogue: C/D layout col=lane&15, row=(lane>>4)*4+j (m89-verified)
    #pragma unroll
    for (int n = 0; n < 4; n++) {
        int col = bn0 + wc * 64 + n * 16 + l16;
        float bb = bred[col];
        #pragma unroll
        for (int m = 0; m < 4; m++) {
            int rowb = bm0 + wr * 64 + m * 16 + lg * 4;
            #pragma unroll
            for (int j = 0; j < 4; j++)
                XR[(size_t)(rowb + j) * SDIM + col] = (_Float16)(acc[m][n][j] + bb);
        }
    }
}

// ---------------------------------------------------------------------------
// Fallback GEMM (round-1 proven): split-bf16 3-term MFMA, fp32 in/out.
// ---------------------------------------------------------------------------
__global__ __launch_bounds__(256, 2)
void vqc_gemm_split(const float* __restrict__ X, const float* __restrict__ W,
                    const float* __restrict__ bred, float* __restrict__ XR)
{
    __shared__ unsigned char lds[65536];
    unsigned char* Ah = lds;
    unsigned char* Al = lds + 16384;
    unsigned char* Bh = lds + 32768;
    unsigned char* Bl = lds + 49152;

    const int t    = threadIdx.x;
    const int lane = t & 63;
    const int w    = t >> 6;
    const int wr   = w >> 1, wc = w & 1;
    const int bm0  = blockIdx.y * 128;
    const int bn0  = blockIdx.x * 128;
    const int l16  = lane & 15;
    const int lg   = lane >> 4;

    f32x4 acc[4][4] = {};

    for (int bk = 0; bk < FDIM; bk += 64) {
        float4 av[8], bv[8];
        #pragma unroll
        for (int i = 0; i < 8; i++) {
            int p   = i * 256 + t;
            int row = p >> 4, c4 = p & 15;
            av[i] = *(const float4*)(X + (size_t)(bm0 + row) * FDIM + bk + c4 * 4);
            bv[i] = *(const float4*)(W + (size_t)(bn0 + row) * FDIM + bk + c4 * 4);
        }
        __syncthreads();
        #pragma unroll
        for (int i = 0; i < 8; i++) {
            int p   = i * 256 + t;
            int row = p >> 4, c4 = p & 15;
            unsigned addr = ((unsigned)(row * 128 + c4 * 8)) ^ ((unsigned)((row & 7) << 4));
            {
                float4 v = av[i];
                unsigned short h0 = f2bf(v.x), h1 = f2bf(v.y), h2 = f2bf(v.z), h3 = f2bf(v.w);
                unsigned short l0 = f2bf(v.x - bf2f(h0)), l1 = f2bf(v.y - bf2f(h1));
                unsigned short l2 = f2bf(v.z - bf2f(h2)), l3 = f2bf(v.w - bf2f(h3));
                *(uint2*)(Ah + addr) = make_uint2((unsigned)h0 | ((unsigned)h1 << 16),
                                                  (unsigned)h2 | ((unsigned)h3 << 16));
                *(uint2*)(Al + addr) = make_uint2((unsigned)l0 | ((unsigned)l1 << 16),
                                                  (unsigned)l2 | ((unsigned)l3 << 16));
            }
            {
                float4 v = bv[i];
                unsigned short h0 = f2bf(v.x), h1 = f2bf(v.y), h2 = f2bf(v.z), h3 = f2bf(v.w);
                unsigned short l0 = f2bf(v.x - bf2f(h0)), l1 = f2bf(v.y - bf2f(h1));
                unsigned short l2 = f2bf(v.z - bf2f(h2)), l3 = f2bf(v.w - bf2f(h3));
                *(uint2*)(Bh + addr) = make_uint2((unsigned)h0 | ((unsigned)h1 << 16),
                                                  (unsigned)h2 | ((unsigned)h3 << 16));
                *(uint2*)(Bl + addr) = make_uint2((unsigned)l0 | ((unsigned)l1 << 16),
                                                  (unsigned)l2 | ((unsigned)l3 << 16));
            }
        }
        __syncthreads();
        #pragma unroll
        for (int ks = 0; ks < 2; ks++) {
            bf16x8 aH[4], aL[4], bH[4], bL[4];
            const int slot = ks * 4 + lg;
            #pragma unroll
            for (int m = 0; m < 4; m++) {
                int row = wr * 64 + m * 16 + l16;
                unsigned off = ((unsigned)(row * 128 + slot * 16)) ^ ((unsigned)((row & 7) << 4));
                aH[m] = *(const bf16x8*)(Ah + off);
                aL[m] = *(const bf16x8*)(Al + off);
            }
            #pragma unroll
            for (int n = 0; n < 4; n++) {
                int row = wc * 64 + n * 16 + l16;
                unsigned off = ((unsigned)(row * 128 + slot * 16)) ^ ((unsigned)((row & 7) << 4));
                bH[n] = *(const bf16x8*)(Bh + off);
                bL[n] = *(const bf16x8*)(Bl + off);
            }
            #pragma unroll
            for (int m = 0; m < 4; m++)
                #pragma unroll
                for (int n = 0; n < 4; n++) {
                    acc[m][n] = __builtin_amdgcn_mfma_f32_16x16x32_bf16(aH[m], bH[n], acc[m][n], 0, 0, 0);
                    acc[m][n] = __builtin_amdgcn_mfma_f32_16x16x32_bf16(aH[m], bL[n], acc[m][n], 0, 0, 0);
                    acc[m][n] = __builtin_amdgcn_mfma_f32_16x16x32_bf16(aL[m], bH[n], acc[m][n], 0, 0, 0);
                }
        }
    }
    #pragma unroll
    for (int n = 0; n < 4; n++) {
        int col = bn0 + wc * 64 + n * 16 + l16;
        float bb = bred[col];
        #pragma unroll
        for (int m = 0; m < 4; m++) {
            int rowb = bm0 + wr * 64 + m * 16 + lg * 4;
            #pragma unroll
            for (int j = 0; j < 4; j++)
                XR[(size_t)(rowb + j) * SDIM + col] = acc[m][n][j] + bb;
        }
    }
}

// ---------------------------------------------------------------------------
// Kernel 2: register-resident quantum circuit.
// State ownership: idx = j*256 + t  (j = 0..15 in registers per thread).
//   q0..q3  (R=2048..256): j-bit pairs  -> pure register ops, no sync
//   q4,q5   (R=128,64)   : t-bits 7,6   -> one LDS exchange, fused 4x4 rotation
//   q6..q11 (R=32..1)    : lane-bit pairs -> __shfl_xor
//   CNOT layer           : LDS write + gathered permutation read
// All LDS accesses are stride-1 across lanes (conflict-free).
// ---------------------------------------------------------------------------
template <typename T>
__global__ __launch_bounds__(256)
void vqc_circuit(const T* __restrict__ XR, const float* __restrict__ theta,
                 const float* __restrict__ W1, const float* __restrict__ b1,
                 const float* __restrict__ W2, const float* __restrict__ b2,
                 const float* __restrict__ W3, const float* __restrict__ b3,
                 float* __restrict__ OUT)
{
    __shared__ float s[SDIM];
    __shared__ float cs_[36], sn_[36];
    __shared__ float wred[4];
    __shared__ float mred[48];

    const int t = threadIdx.x;
    const int lane = t & 63;
    const int w = t >> 6;
    const size_t row = blockIdx.x;
    const T* src = XR + row * SDIM;

    if (t < 36) { float th = theta[t] * 0.5f; cs_[t] = cosf(th); sn_[t] = sinf(th); }

    // load 16 states per thread (idx = j*256 + t) + sum of squares
    float v[16];
    float ss = 0.f;
    #pragma unroll
    for (int j = 0; j < 16; j++) {
        v[j] = (float)src[j * 256 + t];
        ss += v[j] * v[j];
    }
    #pragma unroll
    for (int off = 32; off; off >>= 1) ss += __shfl_down(ss, off);
    if (lane == 0) wred[w] = ss;
    __syncthreads();     // also publishes cs_/sn_
    const float scale = 1.f / (sqrtf(wred[0] + wred[1] + wred[2] + wred[3]) + 1e-10f);
    #pragma unroll
    for (int j = 0; j < 16; j++) v[j] *= scale;

    // composite CNOT-layer permutation for this thread's 16 slots (theta-free)
    int gp[16];
    #pragma unroll
    for (int j = 0; j < 16; j++) {
        int p = j * 256 + t;
        #pragma unroll
        for (int q = 11; q >= 0; q--) {
            const int tq = (q + 1) % 12;
            const int cm = 1 << (11 - q);
            const int tm = 1 << (11 - tq);
            if (p & cm) p ^= tm;
        }
        gp[j] = p;
    }

    const bool ax4 = (t & 128) != 0;   // q4 axis bit
    const bool ax5 = (t & 64) != 0;    // q5 axis bit

    for (int l = 0; l < 3; l++) {
        const int lb = l * 12;
        // ---- q0..q3: register-local (j-bit pairs) ----
        #pragma unroll
        for (int g = 0; g < 4; g++) {
            const int m = 8 >> g;
            const float c = cs_[lb + g], sp = sn_[lb + g];
            float nv[16];
            #pragma unroll
            for (int j = 0; j < 16; j++) {
                float sg = (j & m) ? sp : -sp;
                nv[j] = fmaf(sg, v[j ^ m], c * v[j]);
            }
            #pragma unroll
            for (int j = 0; j < 16; j++) v[j] = nv[j];
        }
        // ---- q4 + q5 fused: one LDS exchange, 4-term composite ----
        __syncthreads();                       // WAR vs previous LDS use
        #pragma unroll
        for (int j = 0; j < 16; j++) s[j * 256 + t] = v[j];
        __syncthreads();
        {
            const float c4 = cs_[lb + 4], s4 = ax4 ? sn_[lb + 4] : -sn_[lb + 4];
            const float c5 = cs_[lb + 5], s5 = ax5 ? sn_[lb + 5] : -sn_[lb + 5];
            const int pA = t ^ 128, pB = t ^ 64, pAB = t ^ 192;
            #pragma unroll
            for (int j = 0; j < 16; j++) {
                float vA  = s[j * 256 + pA];
                float vB  = s[j * 256 + pB];
                float vAB = s[j * 256 + pAB];
                float w_me = fmaf(s4, vA,  c4 * v[j]);   // after q4, own (a,b)
                float w_bf = fmaf(s4, vAB, c4 * vB);     // after q4, b flipped
                v[j] = fmaf(s5, w_bf, c5 * w_me);        // after q5
            }
        }
        // ---- q6..q11: wave shuffles ----
        #pragma unroll
        for (int g = 6; g < 12; g++) {
            const int R = 1 << (11 - g);       // 32,16,8,4,2,1
            const float c = cs_[lb + g];
            const float sg = (t & R) ? sn_[lb + g] : -sn_[lb + g];
            #pragma unroll
            for (int j = 0; j < 16; j++) {
                float vp = __shfl_xor(v[j], R);
                v[j] = fmaf(sg, vp, c * v[j]);
            }
        }
        // ---- CNOT layer: write, barrier, gathered permutation ----
        __syncthreads();                       // WAR vs q4q5 reads
        #pragma unroll
        for (int j = 0; j < 16; j++) s[j * 256 + t] = v[j];
        __syncthreads();
        #pragma unroll
        for (int j = 0; j < 16; j++) v[j] = s[gp[j]];
    }

    // ---- Z-expectations from registers ----
    float mq[12] = {};
    #pragma unroll
    for (int j = 0; j < 16; j++) {
        const int i = j * 256 + t;
        float p = v[j] * v[j];
        #pragma unroll
        for (int q = 0; q < 12; q++)
            mq[q] += ((i >> (11 - q)) & 1) ? -p : p;
    }
    #pragma unroll
    for (int q = 0; q < 12; q++)
        #pragma unroll
        for (int off = 32; off; off >>= 1) mq[q] += __shfl_down(mq[q], off);
    if (lane == 0) {
        #pragma unroll
        for (int q = 0; q < 12; q++) mred[w * 12 + q] = mq[q];
    }
    __syncthreads();

    if (t == 0) {
        float m[12];
        #pragma unroll
        for (int q = 0; q < 12; q++)
            m[q] = mred[q] + mred[12 + q] + mred[24 + q] + mred[36 + q];
        float h1[32];
        for (int k = 0; k < 32; k++) {
            float z = b1[k];
            for (int j = 0; j < 12; j++) z += W1[k * 12 + j] * m[j];
            h1[k] = fmaxf(z, 0.f);
        }
        float h2[16];
        for (int k = 0; k < 16; k++) {
            float z = b2[k];
            for (int j = 0; j < 32; j++) z += W2[k * 32 + j] * h1[j];
            h2[k] = fmaxf(z, 0.f);
        }
        float z = b3[0];
        for (int j = 0; j < 16; j++) z += W3[j] * h2[j];
        OUT[row] = 1.f / (1.f + expf(-z));
    }
}

// ---------------------------------------------------------------------------
extern "C" void kernel_launch(void* const* d_in, const int* in_sizes, int n_in,
                              void* d_out, int out_size, void* d_ws, size_t ws_size,
                              hipStream_t stream)
{
    const float* x     = (const float*)d_in[0];
    const float* W_red = (const float*)d_in[1];
    const float* b_red = (const float*)d_in[2];
    const float* theta = (const float*)d_in[3];
    const float* W1    = (const float*)d_in[4];
    const float* b1    = (const float*)d_in[5];
    const float* W2    = (const float*)d_in[6];
    const float* b2    = (const float*)d_in[7];
    const float* W3    = (const float*)d_in[8];
    const float* b3    = (const float*)d_in[9];
    float* out = (float*)d_out;

    const size_t SZ_XH = (size_t)BATCH * FDIM * 2;   // 128 MiB
    const size_t SZ_WH = (size_t)SDIM * FDIM * 2;    //  64 MiB
    const size_t SZ_XR = (size_t)BATCH * SDIM * 2;   //  64 MiB
    const size_t NEED  = SZ_XH + SZ_WH + SZ_XR;      // 256 MiB

    if (ws_size >= NEED) {
        _Float16* Xh = (_Float16*)d_ws;
        _Float16* Wh = (_Float16*)((char*)d_ws + SZ_XH);
        _Float16* xr = (_Float16*)((char*)d_ws + SZ_XH + SZ_WH);
        cvt_fp16<<<2048, 256, 0, stream>>>(x, Xh, (unsigned)((size_t)BATCH * FDIM / 8));
        cvt_fp16<<<1024, 256, 0, stream>>>(W_red, Wh, (unsigned)((size_t)SDIM * FDIM / 8));
        dim3 g1(SDIM / 128, BATCH / 128);   // (32, 64)
        vqc_gemm_f16<<<g1, 256, 0, stream>>>(Xh, Wh, b_red, xr);
        vqc_circuit<_Float16><<<BATCH, 256, 0, stream>>>(xr, theta, W1, b1, W2, b2, W3, b3, out);
    } else {
        float* xr = (float*)d_ws;   // 128 MiB
        dim3 g1(SDIM / 128, BATCH / 128);
        vqc_gemm_split<<<g1, 256, 0, stream>>>(x, W_red, b_red, xr);
        vqc_circuit<float><<<BATCH, 256, 0, stream>>>(xr, theta, W1, b1, W2, b2, W3, b3, out);
    }
}